// Round 19
// baseline (314.313 us; speedup 1.0000x reference)
//
#include <hip/hip_runtime.h>
#include <hip/hip_bf16.h>

typedef short bf16x8 __attribute__((ext_vector_type(8)));
typedef float f32x4 __attribute__((ext_vector_type(4)));
typedef float f32x16 __attribute__((ext_vector_type(16)));

#define NH 12
#define SEQ 1792
#define DMODEL 1536
#define HD 128

static __device__ __forceinline__ void gload16(const void* g, void* l) {
  __builtin_amdgcn_global_load_lds((const __attribute__((address_space(1))) void*)g,
                                   (__attribute__((address_space(3))) void*)l, 16, 0, 0);
}

static __device__ __forceinline__ short f2bf(float x) {
  __hip_bfloat16 h = __float2bfloat16(x);
  return *reinterpret_cast<short*>(&h);
}

static __device__ __forceinline__ unsigned pack2(float lo, float hi) {
  unsigned a = (unsigned)(unsigned short)f2bf(lo);
  unsigned b = (unsigned)(unsigned short)f2bf(hi);
  return a | (b << 16);
}

// ---------- fused fp32 -> bf16 cast for x + Wq + Wk + Wv + Wo (one launch) ----------
__global__ __launch_bounds__(256) void cast_all_kernel(
    const float* __restrict__ x, const float* __restrict__ wq, const float* __restrict__ wk,
    const float* __restrict__ wv, const float* __restrict__ wo,
    __hip_bfloat16* __restrict__ xb, __hip_bfloat16* __restrict__ wb,
    __hip_bfloat16* __restrict__ wob) {
  int i = blockIdx.x * 256 + threadIdx.x;
  const float* src; __hip_bfloat16* dst; int j;
  if (i < 2752512)      { src = x;  dst = xb;            j = i; }
  else if (i < 3342336) { src = wq; dst = wb;            j = i - 2752512; }
  else if (i < 3932160) { src = wk; dst = wb + 2359296;  j = i - 3342336; }
  else if (i < 4521984) { src = wv; dst = wb + 4718592;  j = i - 3932160; }
  else if (i < 5111808) { src = wo; dst = wob;           j = i - 4521984; }
  else return;
  float4 v = reinterpret_cast<const float4*>(src)[j];
  short4 r;
  r.x = f2bf(v.x); r.y = f2bf(v.y); r.z = f2bf(v.z); r.w = f2bf(v.w);
  reinterpret_cast<short4*>(dst)[j] = r;
}

// ---------- 256x128 bf16 GEMM, BK=32, 4 waves, 2 blocks/CU (R18, best measured) ----------
template<int MODE>
__global__ __launch_bounds__(256, 2) void gemm_km(
    const __hip_bfloat16* __restrict__ A, const __hip_bfloat16* __restrict__ B,
    int nN, int cpx,
    const float* __restrict__ bq, const float* __restrict__ bk, const float* __restrict__ bv,
    __hip_bfloat16* __restrict__ qbuf, __hip_bfloat16* __restrict__ kbuf,
    __hip_bfloat16* __restrict__ vt,
    const float* __restrict__ bo, float* __restrict__ outp)
{
  constexpr int K = DMODEL;                  // 1536
  constexpr int nT = K / 32;                 // 48 K-tiles of 32
  __shared__ char LDSRAW[65536];             // [0,32768): A dbuf; [32768,49152): B dbuf
  const int tid = threadIdx.x;               // 0..255
  const int l = tid & 63, w = tid >> 6;      // 4 waves
  const int lr = l & 15, lg = l >> 4;
  const int wr = w >> 1, wc = w & 1;         // 2 x 2 wave grid

  const int orig = blockIdx.x;               // bijective XCD swizzle (grid = 8*cpx)
  const int wg = (orig & 7) * cpx + (orig >> 3);
  const int m0 = (wg / nN) * 256, n0 = (wg % nN) * 128;

  auto stage = [&](int t) {
    char* Ad = LDSRAW + (t & 1) * 16384;
    char* Bd = LDSRAW + 32768 + (t & 1) * 8192;
#pragma unroll
    for (int c4 = 0; c4 < 4; ++c4) {         // A: 1024 chunks of 16B
      int chunk = c4 * 256 + tid;
      int row = chunk >> 2;                  // 4 chunks per 64B row
      int scol = ((chunk & 3) << 4) ^ ((row & 3) << 4);
      gload16((const char*)A + (size_t)(m0 + row) * (K * 2) + t * 64 + scol,
              Ad + chunk * 16);
    }
#pragma unroll
    for (int c2 = 0; c2 < 2; ++c2) {         // B: 512 chunks of 16B
      int chunk = c2 * 256 + tid;
      int row = chunk >> 2;                  // 0..127
      int scol = ((chunk & 3) << 4) ^ ((row & 3) << 4);
      gload16((const char*)B + (size_t)(n0 + row) * (K * 2) + t * 64 + scol,
              Bd + chunk * 16);
    }
  };

  f32x4 acc[8][4] = {};

  stage(0);
  for (int t = 0; t < nT; ++t) {
    __syncthreads();                         // stage(t) drained; prev reads done
    if (t + 1 < nT) stage(t + 1);
    const char* Al = LDSRAW + (t & 1) * 16384;
    const char* Bl = LDSRAW + 32768 + (t & 1) * 8192;
    bf16x8 afr[8], bfr[4];
#pragma unroll
    for (int fi = 0; fi < 8; ++fi) {
      int row = wr * 128 + fi * 16 + lr;
      afr[fi] = *reinterpret_cast<const bf16x8*>(
          Al + row * 64 + ((lg * 16) ^ ((row & 3) << 4)));
    }
#pragma unroll
    for (int fj = 0; fj < 4; ++fj) {
      int row = wc * 64 + fj * 16 + lr;
      bfr[fj] = *reinterpret_cast<const bf16x8*>(
          Bl + row * 64 + ((lg * 16) ^ ((row & 3) << 4)));
    }
    __builtin_amdgcn_s_setprio(1);
#pragma unroll
    for (int fi = 0; fi < 8; ++fi)
#pragma unroll
      for (int fj = 0; fj < 4; ++fj)
        acc[fi][fj] = __builtin_amdgcn_mfma_f32_16x16x32_bf16(afr[fi], bfr[fj], acc[fi][fj], 0, 0, 0);
    __builtin_amdgcn_s_setprio(0);
  }

  // ---- epilogue ----
  if (MODE == 0) {
    const int which = n0 / DMODEL;            // uniform per block (128 | 1536)
    const int bbb = m0 / SEQ;                 // m-tiles never span batch (1792=7*256)
    const int sr0 = m0 - bbb * SEQ;
    if (which < 2) {
#pragma unroll
      for (int fj = 0; fj < 4; ++fj) {
        int ncol = n0 + wc * 64 + fj * 16 + lr;
        int cc = ncol - which * DMODEL;
        int hh = cc >> 7, dd = cc & 127;
        float bias = (which == 0 ? bq : bk)[cc];
#pragma unroll
        for (int fi = 0; fi < 8; ++fi)
#pragma unroll
          for (int r = 0; r < 4; ++r) {
            int sr = sr0 + wr * 128 + fi * 16 + lg * 4 + r;
            __hip_bfloat16 hv = __float2bfloat16(acc[fi][fj][r] + bias);
            if (which == 0)
              qbuf[(((size_t)(bbb * NH + hh)) * SEQ + sr) * HD + dd] = hv;
            else
              kbuf[(((size_t)(bbb * NH + hh)) * SEQ + sr) * HD + dd] = hv;
          }
      }
    } else {
      // v: LDS transpose bounce [d 128][s 256] -> coalesced b128 stores to vt[d][s]
      __syncthreads();                        // K-loop LDS dead
      const int cc0 = n0 - 2 * DMODEL;        // multiple of 128 -> single head
#pragma unroll
      for (int fj = 0; fj < 4; ++fj) {
        int d_loc = wc * 64 + fj * 16 + lr;   // 0..127
        float bias = bv[cc0 + d_loc];
#pragma unroll
        for (int fi = 0; fi < 8; ++fi)
#pragma unroll
          for (int r = 0; r < 4; ++r) {
            int s_loc = wr * 128 + fi * 16 + lg * 4 + r;   // 0..255
            *reinterpret_cast<short*>(LDSRAW + d_loc * 512 +
                ((s_loc * 2) ^ ((d_loc & 7) << 4))) = f2bf(acc[fi][fj][r] + bias);
          }
      }
      __syncthreads();
      const int hh = (cc0 >> 7);
#pragma unroll
      for (int c = 0; c < 16; ++c) {
        int g = c * 256 + tid;                // 16B chunk id in [0,4096)
        int d = g >> 5;                       // 32 chunks per 512B d-row
        int sb = (g & 31) << 4;               // byte offset within row
        bf16x8 vvv = *reinterpret_cast<const bf16x8*>(
            LDSRAW + d * 512 + (sb ^ ((d & 7) << 4)));
        int dd = (cc0 + d) & 127;
        *reinterpret_cast<bf16x8*>(
            &vt[(((size_t)(bbb * NH + hh)) * HD + dd) * SEQ + sr0 + (sb >> 1)]) = vvv;
      }
    }
  } else {
#pragma unroll
    for (int fj = 0; fj < 4; ++fj) {
      int ncol = n0 + wc * 64 + fj * 16 + lr;
      float bias = bo[ncol];
#pragma unroll
      for (int fi = 0; fi < 8; ++fi)
#pragma unroll
        for (int r = 0; r < 4; ++r) {
          int rowg = m0 + wr * 128 + fi * 16 + lg * 4 + r;
          outp[(size_t)rowg * DMODEL + ncol] = acc[fi][fj][r] + bias;
        }
    }
  }
}

// ---------- RMSNorm (full-D) + 3D-grid RoPE, in-place on q,k ----------
// q pre-scaled by log2(e)/sqrt(HD): attention softmax runs in exp2 domain.
__global__ __launch_bounds__(256) void rmsrope_kernel(
    __hip_bfloat16* __restrict__ qb, __hip_bfloat16* __restrict__ kb,
    const float* __restrict__ gq, const float* __restrict__ gk,
    const float* __restrict__ fc, const float* __restrict__ fs,
    const int* __restrict__ gsz, const int* __restrict__ nmod)
{
  const int bs = blockIdx.x;
  const int b = bs / SEQ, s = bs - b * SEQ;
  const int t = threadIdx.x;
  const int f = gsz[0], h = gsz[1], wd = gsz[2];
  const int mm = nmod[0];
  const int seq_per = f * h * wd;
  int total_len = seq_per * mm; if (total_len > SEQ) total_len = SEQ;
  const bool dorope = s < total_len;
  int fi = 0, hi2 = 0, wi = 0;
  if (dorope) {
    int p = s % seq_per;
    fi = p / (h * wd);
    int rem = p - fi * (h * wd);
    hi2 = rem / wd;
    wi = rem - hi2 * wd;
  }
  float qv[3][2], kv[3][2];
  float sq = 0.f, sk = 0.f;
#pragma unroll
  for (int r = 0; r < 3; ++r) {
    int pi = t + r * 256;
    int head = pi >> 6;
    int dd = (pi & 63) * 2;
    size_t addr = (((size_t)(b * NH + head)) * SEQ + s) * HD + dd;
    __hip_bfloat162 q2 = *reinterpret_cast<const __hip_bfloat162*>(&qb[addr]);
    __hip_bfloat162 k2 = *reinterpret_cast<const __hip_bfloat162*>(&kb[addr]);
    qv[r][0] = __bfloat162float(q2.x); qv[r][1] = __bfloat162float(q2.y);
    kv[r][0] = __bfloat162float(k2.x); kv[r][1] = __bfloat162float(k2.y);
    sq += qv[r][0] * qv[r][0] + qv[r][1] * qv[r][1];
    sk += kv[r][0] * kv[r][0] + kv[r][1] * kv[r][1];
  }
#pragma unroll
  for (int off = 1; off < 64; off <<= 1) {
    sq += __shfl_xor(sq, off);
    sk += __shfl_xor(sk, off);
  }
  __shared__ float red[2][4];
  if ((t & 63) == 0) { red[0][t >> 6] = sq; red[1][t >> 6] = sk; }
  __syncthreads();
  float tq = red[0][0] + red[0][1] + red[0][2] + red[0][3];
  float tk = red[1][0] + red[1][1] + red[1][2] + red[1][3];
  float rq = rsqrtf(tq * (1.0f / DMODEL) + 1e-6f);
  float rk = rsqrtf(tk * (1.0f / DMODEL) + 1e-6f);
  const float scale = 0.12751743f; // log2(e)/sqrt(128), folded into q (exp2 softmax)
#pragma unroll
  for (int r = 0; r < 3; ++r) {
    int pi = t + r * 256;
    int head = pi >> 6;
    int dd = (pi & 63) * 2;
    int col = pi * 2;
    size_t addr = (((size_t)(b * NH + head)) * SEQ + s) * HD + dd;
    float q0 = qv[r][0] * rq * gq[col], q1 = qv[r][1] * rq * gq[col + 1];
    float k0 = kv[r][0] * rk * gk[col], k1 = kv[r][1] * rk * gk[col + 1];
    if (dorope) {
      int j = pi & 63;
      int row = (j < 22) ? fi : (j < 43) ? hi2 : wi;
      float co = fc[row * 64 + j], si = fs[row * 64 + j];
      float a;
      a = q0 * co - q1 * si; q1 = q0 * si + q1 * co; q0 = a;
      a = k0 * co - k1 * si; k1 = k0 * si + k1 * co; k0 = a;
    }
    q0 *= scale; q1 *= scale;
    __hip_bfloat162 oq, ok;
    oq.x = __float2bfloat16(q0); oq.y = __float2bfloat16(q1);
    ok.x = __float2bfloat16(k0); ok.y = __float2bfloat16(k1);
    *reinterpret_cast<__hip_bfloat162*>(&qb[addr]) = oq;
    *reinterpret_cast<__hip_bfloat162*>(&kb[addr]) = ok;
  }
}

// ---------- flash attention v13: full-rank LDS swizzles + exp2 softmax ----------
// K (256B rows, 16 slots): byte ^= ((row>>1)&15)<<4 -> conflict-free (2-way only).
// V (128B rows,  8 slots): byte ^= ((row>>2)&7)<<4  -> conflict-free (2-way only).
// Softmax in exp2 domain (log2e folded into q scale); defer threshold 11.54.
__global__ __launch_bounds__(256, 2) void attn_kernel(
    const __hip_bfloat16* __restrict__ qb, const __hip_bfloat16* __restrict__ kbuf,
    const __hip_bfloat16* __restrict__ vt, const int* __restrict__ seq_lens,
    __hip_bfloat16* __restrict__ ob)
{
  const int orig = blockIdx.x;
  const int wg = (orig & 7) * 84 + (orig >> 3);
  const int bh = wg / 14, qt = wg % 14;
  const int bbb = bh / NH, hh = bh - bbb * NH;
  const int tid = threadIdx.x;
  const int w = tid >> 6, l = tid & 63;
  const int lq = l & 31, h = l >> 5;
  const int sl = seq_lens[bbb];
  const __hip_bfloat16* Q = qb + (size_t)bh * SEQ * HD;
  const char* Kc = (const char*)(kbuf + (size_t)bh * SEQ * HD);
  const __hip_bfloat16* Vp = vt + (size_t)bh * HD * SEQ;   // [128][1792]
  const int q0 = qt * 128 + w * 32;

  __shared__ __hip_bfloat16 Kt[2][64 * 128];   // 32 KB, 256B rows
  __shared__ __hip_bfloat16 Vt[128 * 64];      // 16 KB single buffer, 128B rows

  bf16x8 qf[8];
#pragma unroll
  for (int kc = 0; kc < 8; ++kc)
    qf[kc] = *reinterpret_cast<const bf16x8*>(
        &Q[(size_t)(q0 + lq) * HD + kc * 16 + h * 8]);

  f32x16 oacc[4] = {};                          // O[q_off][d0*32+lq]
  float m = -3e38f, ll = 0.f;                   // per-lane q-row softmax state

  const int nkt = (sl + 63) >> 6;

  auto stageK = [&](int buf, int k0) {
    char* Lb = (char*)&Kt[buf][0];
#pragma unroll
    for (int q2 = 0; q2 < 4; ++q2) {
      int chunk = q2 * 256 + tid;               // 16B chunk id in [0,1024)
      int row = chunk >> 4;                     // 16 chunks per 256B row
      int scb = (((chunk & 15) ^ ((row >> 1) & 15)) << 4);  // inverse full-rank swz
      gload16(Kc + (size_t)(k0 + row) * 256 + scb, Lb + chunk * 16);
    }
  };
  auto stageV = [&](int k0) {
    char* Lb = (char*)&Vt[0];
#pragma unroll
    for (int q2 = 0; q2 < 4; ++q2) {
      int chunk = q2 * 256 + tid;               // 16B chunk id in [0,1024)
      int row = chunk >> 3;                     // 8 chunks per 128B row; row = d
      int scb = (((chunk & 7) ^ ((row >> 2) & 7)) << 4);    // inverse full-rank swz
      gload16(Vp + (size_t)row * SEQ + k0 + (scb >> 1), Lb + chunk * 16);
    }
  };

  stageK(0, 0);
  for (int kt = 0; kt < nkt; ++kt) {
    __syncthreads();                            // K(kt) landed everywhere; Vt reads done
    const int k0 = kt * 64;
    stageV(k0);                                 // V first (oldest in vmcnt queue)
    const bool pf = (kt + 1 < nkt);
    if (pf) stageK((kt + 1) & 1, k0 + 64);      // K prefetch after
    const char* Kl = (const char*)&Kt[kt & 1][0];
    const char* Vl = (const char*)&Vt[0];

    // swapped QK^T: S^T[k][q], 16 ds_read_b128 + 16 mfma_32x32x16
    f32x16 sa[2] = {};
#pragma unroll
    for (int cb = 0; cb < 2; ++cb) {
      int row = cb * 32 + lq;
      int swz = ((row >> 1) & 15) << 4;
#pragma unroll
      for (int kc = 0; kc < 8; ++kc) {
        bf16x8 kf = *reinterpret_cast<const bf16x8*>(
            Kl + row * 256 + ((kc * 32 + h * 16) ^ swz));
        sa[cb] = __builtin_amdgcn_mfma_f32_32x32x16_bf16(kf, qf[kc], sa[cb], 0, 0, 0);
      }
    }

    // mask tail (rare)
    if (k0 + 64 > sl) {
#pragma unroll
      for (int cb = 0; cb < 2; ++cb)
#pragma unroll
        for (int r = 0; r < 16; ++r) {
          int kg = k0 + cb * 32 + (r & 3) + 8 * (r >> 2) + 4 * h;
          if (kg >= sl) sa[cb][r] = -3e38f;
        }
    }

    // in-register online softmax (exp2 domain)
    float mx = -3e38f;
#pragma unroll
    for (int cb = 0; cb < 2; ++cb)
#pragma unroll
      for (int r = 0; r < 16; ++r) mx = fmaxf(mx, sa[cb][r]);
    mx = fmaxf(mx, __shfl_xor(mx, 32));

    if (__any(mx - m > 11.54f)) {               // defer-max (T13; 8*log2e)
      float mn = fmaxf(m, mx);
      float alpha = exp2f(m - mn);
      m = mn;
      ll *= alpha;
#pragma unroll
      for (int r = 0; r < 16; ++r) {
        float ar = __shfl(alpha, (r & 3) + 8 * (r >> 2) + 4 * h);
#pragma unroll
        for (int d0 = 0; d0 < 4; ++d0) oacc[d0][r] *= ar;
      }
    }

    float rs = 0.f;
#pragma unroll
    for (int cb = 0; cb < 2; ++cb)
#pragma unroll
      for (int r = 0; r < 16; ++r) {
        float e = exp2f(sa[cb][r] - m);
        sa[cb][r] = e;
        rs += e;
      }
    rs += __shfl_xor(rs, 32);
    ll += rs;

    // V(kt) visibility: my V retired (counted) + all waves' V retired (barrier)
    if (pf) asm volatile("s_waitcnt vmcnt(4)" ::: "memory");
    else    asm volatile("s_waitcnt vmcnt(0)" ::: "memory");
    __builtin_amdgcn_s_barrier();

    // P -> bf16 A-frags and PV (V from LDS)
#pragma unroll
    for (int c = 0; c < 4; ++c) {
      const int cb = c >> 1, r0 = 8 * (c & 1);
      unsigned A01 = pack2(sa[cb][r0],     sa[cb][r0 + 1]);
      unsigned A23 = pack2(sa[cb][r0 + 2], sa[cb][r0 + 3]);
      unsigned B01 = pack2(sa[cb][r0 + 4], sa[cb][r0 + 5]);
      unsigned B23 = pack2(sa[cb][r0 + 6], sa[cb][r0 + 7]);
      unsigned s1 = __shfl_xor(h ? A01 : B01, 32);
      unsigned s2 = __shfl_xor(h ? A23 : B23, 32);
      int4 wv;
      wv.x = (int)(h ? s1 : A01);
      wv.y = (int)(h ? s2 : A23);
      wv.z = (int)(h ? B01 : s1);
      wv.w = (int)(h ? B23 : s2);
      bf16x8 pa = *reinterpret_cast<bf16x8*>(&wv);
#pragma unroll
      for (int d0 = 0; d0 < 4; ++d0) {
        int vr = d0 * 32 + lq;
        bf16x8 vv = *reinterpret_cast<const bf16x8*>(
            Vl + vr * 128 + ((c * 32 + h * 16) ^ (((vr >> 2) & 7) << 4)));
        oacc[d0] = __builtin_amdgcn_mfma_f32_32x32x16_bf16(pa, vv, oacc[d0], 0, 0, 0);
      }
    }
  }

  float invl = 1.0f / ll;
#pragma unroll
  for (int r = 0; r < 16; ++r) {
    int qoff = (r & 3) + 8 * (r >> 2) + 4 * h;
    float ir = __shfl(invl, qoff);
    int qrow = q0 + qoff;
#pragma unroll
    for (int d0 = 0; d0 < 4; ++d0)
      ob[((size_t)bbb * SEQ + qrow) * DMODEL + hh * HD + d0 * 32 + lq] =
          __float2bfloat16(oacc[d0][r] * ir);
  }
}

// ---------- launch ----------
extern "C" void kernel_launch(void* const* d_in, const int* in_sizes, int n_in,
                              void* d_out, int out_size, void* d_ws, size_t ws_size,
                              hipStream_t stream) {
  const float* x   = (const float*)d_in[0];
  const int* seq_lens   = (const int*)d_in[1];
  const int* grid_sizes = (const int*)d_in[2];
  const float* fc  = (const float*)d_in[3];
  const float* fs  = (const float*)d_in[4];
  const float* Wq  = (const float*)d_in[5];
  const float* bq  = (const float*)d_in[6];
  const float* Wk  = (const float*)d_in[7];
  const float* bk  = (const float*)d_in[8];
  const float* Wv  = (const float*)d_in[9];
  const float* bv  = (const float*)d_in[10];
  const float* Wo  = (const float*)d_in[11];
  const float* bo  = (const float*)d_in[12];
  const float* gq  = (const float*)d_in[13];
  const float* gk  = (const float*)d_in[14];
  const int* nmod  = (const int*)d_in[15];
  float* out = (float*)d_out;

  char* ws = (char*)d_ws;
  __hip_bfloat16* xb   = (__hip_bfloat16*)(ws + 0);           // [7168][1536]
  __hip_bfloat16* wb   = (__hip_bfloat16*)(ws + 22020096);    // [4608][1536]
  __hip_bfloat16* wob  = (__hip_bfloat16*)(ws + 36175872);    // [1536][1536]
  __hip_bfloat16* qbuf = (__hip_bfloat16*)(ws + 40894464);    // [48][1792][128]
  __hip_bfloat16* kbuf = (__hip_bfloat16*)(ws + 62914560);    // [48][1792][128]
  __hip_bfloat16* vtb  = (__hip_bfloat16*)(ws + 84934656);    // [48][128][1792]
  __hip_bfloat16* ob   = xb;                                  // O reuses xb region

  cast_all_kernel<<<(5111808 + 255) / 256, 256, 0, stream>>>(x, Wq, Wk, Wv, Wo, xb, wb, wob);

  // QKV: M=7168 (28 tiles of 256) x N=4608 (36 tiles of 128) -> 1008 = 8*126
  gemm_km<0><<<1008, 256, 0, stream>>>(xb, wb, 36, 126, bq, bk, bv,
                                       qbuf, kbuf, vtb, nullptr, nullptr);
  rmsrope_kernel<<<7168, 256, 0, stream>>>(qbuf, kbuf, gq, gk, fc, fs, grid_sizes, nmod);
  attn_kernel<<<672, 256, 0, stream>>>(qbuf, kbuf, vtb, seq_lens, ob);
  // out-proj: M=7168 (28) x N=1536 (12 tiles of 128) -> 336 = 8*42
  gemm_km<1><<<336, 256, 0, stream>>>(ob, wob, 12, 42, nullptr, nullptr, nullptr,
                                      nullptr, nullptr, nullptr, bo, out);
}

// Round 20
// 301.194 us; speedup vs baseline: 1.0436x; 1.0436x over previous
//
#include <hip/hip_runtime.h>
#include <hip/hip_bf16.h>

typedef short bf16x8 __attribute__((ext_vector_type(8)));
typedef float f32x4 __attribute__((ext_vector_type(4)));
typedef float f32x16 __attribute__((ext_vector_type(16)));

#define NH 12
#define SEQ 1792
#define DMODEL 1536
#define HD 128

static __device__ __forceinline__ void gload16(const void* g, void* l) {
  __builtin_amdgcn_global_load_lds((const __attribute__((address_space(1))) void*)g,
                                   (__attribute__((address_space(3))) void*)l, 16, 0, 0);
}

static __device__ __forceinline__ short f2bf(float x) {
  __hip_bfloat16 h = __float2bfloat16(x);
  return *reinterpret_cast<short*>(&h);
}

static __device__ __forceinline__ unsigned pack2(float lo, float hi) {
  unsigned a = (unsigned)(unsigned short)f2bf(lo);
  unsigned b = (unsigned)(unsigned short)f2bf(hi);
  return a | (b << 16);
}

// ---------- fused fp32 -> bf16 cast for x + Wq + Wk + Wv + Wo (one launch) ----------
__global__ __launch_bounds__(256) void cast_all_kernel(
    const float* __restrict__ x, const float* __restrict__ wq, const float* __restrict__ wk,
    const float* __restrict__ wv, const float* __restrict__ wo,
    __hip_bfloat16* __restrict__ xb, __hip_bfloat16* __restrict__ wb,
    __hip_bfloat16* __restrict__ wob) {
  int i = blockIdx.x * 256 + threadIdx.x;
  const float* src; __hip_bfloat16* dst; int j;
  if (i < 2752512)      { src = x;  dst = xb;            j = i; }
  else if (i < 3342336) { src = wq; dst = wb;            j = i - 2752512; }
  else if (i < 3932160) { src = wk; dst = wb + 2359296;  j = i - 3342336; }
  else if (i < 4521984) { src = wv; dst = wb + 4718592;  j = i - 3932160; }
  else if (i < 5111808) { src = wo; dst = wob;           j = i - 4521984; }
  else return;
  float4 v = reinterpret_cast<const float4*>(src)[j];
  short4 r;
  r.x = f2bf(v.x); r.y = f2bf(v.y); r.z = f2bf(v.z); r.w = f2bf(v.w);
  reinterpret_cast<short4*>(dst)[j] = r;
}

// ---------- 256x128 bf16 GEMM, BK=32, 4 waves, 2 blocks/CU (R18, best measured) ----------
template<int MODE>
__global__ __launch_bounds__(256, 2) void gemm_km(
    const __hip_bfloat16* __restrict__ A, const __hip_bfloat16* __restrict__ B,
    int nN, int cpx,
    const float* __restrict__ bq, const float* __restrict__ bk, const float* __restrict__ bv,
    __hip_bfloat16* __restrict__ qbuf, __hip_bfloat16* __restrict__ kbuf,
    __hip_bfloat16* __restrict__ vt,
    const float* __restrict__ bo, float* __restrict__ outp)
{
  constexpr int K = DMODEL;                  // 1536
  constexpr int nT = K / 32;                 // 48 K-tiles of 32
  __shared__ char LDSRAW[65536];             // [0,32768): A dbuf; [32768,49152): B dbuf
  const int tid = threadIdx.x;               // 0..255
  const int l = tid & 63, w = tid >> 6;      // 4 waves
  const int lr = l & 15, lg = l >> 4;
  const int wr = w >> 1, wc = w & 1;         // 2 x 2 wave grid

  const int orig = blockIdx.x;               // bijective XCD swizzle (grid = 8*cpx)
  const int wg = (orig & 7) * cpx + (orig >> 3);
  const int m0 = (wg / nN) * 256, n0 = (wg % nN) * 128;

  auto stage = [&](int t) {
    char* Ad = LDSRAW + (t & 1) * 16384;
    char* Bd = LDSRAW + 32768 + (t & 1) * 8192;
#pragma unroll
    for (int c4 = 0; c4 < 4; ++c4) {         // A: 1024 chunks of 16B
      int chunk = c4 * 256 + tid;
      int row = chunk >> 2;                  // 4 chunks per 64B row
      int scol = ((chunk & 3) << 4) ^ ((row & 3) << 4);
      gload16((const char*)A + (size_t)(m0 + row) * (K * 2) + t * 64 + scol,
              Ad + chunk * 16);
    }
#pragma unroll
    for (int c2 = 0; c2 < 2; ++c2) {         // B: 512 chunks of 16B
      int chunk = c2 * 256 + tid;
      int row = chunk >> 2;                  // 0..127
      int scol = ((chunk & 3) << 4) ^ ((row & 3) << 4);
      gload16((const char*)B + (size_t)(n0 + row) * (K * 2) + t * 64 + scol,
              Bd + chunk * 16);
    }
  };

  f32x4 acc[8][4] = {};

  stage(0);
  for (int t = 0; t < nT; ++t) {
    __syncthreads();                         // stage(t) drained; prev reads done
    if (t + 1 < nT) stage(t + 1);
    const char* Al = LDSRAW + (t & 1) * 16384;
    const char* Bl = LDSRAW + 32768 + (t & 1) * 8192;
    bf16x8 afr[8], bfr[4];
#pragma unroll
    for (int fi = 0; fi < 8; ++fi) {
      int row = wr * 128 + fi * 16 + lr;
      afr[fi] = *reinterpret_cast<const bf16x8*>(
          Al + row * 64 + ((lg * 16) ^ ((row & 3) << 4)));
    }
#pragma unroll
    for (int fj = 0; fj < 4; ++fj) {
      int row = wc * 64 + fj * 16 + lr;
      bfr[fj] = *reinterpret_cast<const bf16x8*>(
          Bl + row * 64 + ((lg * 16) ^ ((row & 3) << 4)));
    }
    __builtin_amdgcn_s_setprio(1);
#pragma unroll
    for (int fi = 0; fi < 8; ++fi)
#pragma unroll
      for (int fj = 0; fj < 4; ++fj)
        acc[fi][fj] = __builtin_amdgcn_mfma_f32_16x16x32_bf16(afr[fi], bfr[fj], acc[fi][fj], 0, 0, 0);
    __builtin_amdgcn_s_setprio(0);
  }

  // ---- epilogue ----
  if (MODE == 0) {
    const int which = n0 / DMODEL;            // uniform per block (128 | 1536)
    const int bbb = m0 / SEQ;                 // m-tiles never span batch (1792=7*256)
    const int sr0 = m0 - bbb * SEQ;
    if (which < 2) {
#pragma unroll
      for (int fj = 0; fj < 4; ++fj) {
        int ncol = n0 + wc * 64 + fj * 16 + lr;
        int cc = ncol - which * DMODEL;
        int hh = cc >> 7, dd = cc & 127;
        float bias = (which == 0 ? bq : bk)[cc];
#pragma unroll
        for (int fi = 0; fi < 8; ++fi)
#pragma unroll
          for (int r = 0; r < 4; ++r) {
            int sr = sr0 + wr * 128 + fi * 16 + lg * 4 + r;
            __hip_bfloat16 hv = __float2bfloat16(acc[fi][fj][r] + bias);
            if (which == 0)
              qbuf[(((size_t)(bbb * NH + hh)) * SEQ + sr) * HD + dd] = hv;
            else
              kbuf[(((size_t)(bbb * NH + hh)) * SEQ + sr) * HD + dd] = hv;
          }
      }
    } else {
      // v: LDS transpose bounce [d 128][s 256] -> coalesced b128 stores to vt[d][s]
      __syncthreads();                        // K-loop LDS dead
      const int cc0 = n0 - 2 * DMODEL;        // multiple of 128 -> single head
#pragma unroll
      for (int fj = 0; fj < 4; ++fj) {
        int d_loc = wc * 64 + fj * 16 + lr;   // 0..127
        float bias = bv[cc0 + d_loc];
#pragma unroll
        for (int fi = 0; fi < 8; ++fi)
#pragma unroll
          for (int r = 0; r < 4; ++r) {
            int s_loc = wr * 128 + fi * 16 + lg * 4 + r;   // 0..255
            *reinterpret_cast<short*>(LDSRAW + d_loc * 512 +
                ((s_loc * 2) ^ ((d_loc & 7) << 4))) = f2bf(acc[fi][fj][r] + bias);
          }
      }
      __syncthreads();
      const int hh = (cc0 >> 7);
#pragma unroll
      for (int c = 0; c < 16; ++c) {
        int g = c * 256 + tid;                // 16B chunk id in [0,4096)
        int d = g >> 5;                       // 32 chunks per 512B d-row
        int sb = (g & 31) << 4;               // byte offset within row
        bf16x8 vvv = *reinterpret_cast<const bf16x8*>(
            LDSRAW + d * 512 + (sb ^ ((d & 7) << 4)));
        int dd = (cc0 + d) & 127;
        *reinterpret_cast<bf16x8*>(
            &vt[(((size_t)(bbb * NH + hh)) * HD + dd) * SEQ + sr0 + (sb >> 1)]) = vvv;
      }
    }
  } else {
#pragma unroll
    for (int fj = 0; fj < 4; ++fj) {
      int ncol = n0 + wc * 64 + fj * 16 + lr;
      float bias = bo[ncol];
#pragma unroll
      for (int fi = 0; fi < 8; ++fi)
#pragma unroll
        for (int r = 0; r < 4; ++r) {
          int rowg = m0 + wr * 128 + fi * 16 + lg * 4 + r;
          outp[(size_t)rowg * DMODEL + ncol] = acc[fi][fj][r] + bias;
        }
    }
  }
}

// ---------- RMSNorm (full-D) + 3D-grid RoPE, in-place on q,k ----------
// q additionally pre-scaled by 1/sqrt(HD) so attention skips the scale.
__global__ __launch_bounds__(256) void rmsrope_kernel(
    __hip_bfloat16* __restrict__ qb, __hip_bfloat16* __restrict__ kb,
    const float* __restrict__ gq, const float* __restrict__ gk,
    const float* __restrict__ fc, const float* __restrict__ fs,
    const int* __restrict__ gsz, const int* __restrict__ nmod)
{
  const int bs = blockIdx.x;
  const int b = bs / SEQ, s = bs - b * SEQ;
  const int t = threadIdx.x;
  const int f = gsz[0], h = gsz[1], wd = gsz[2];
  const int mm = nmod[0];
  const int seq_per = f * h * wd;
  int total_len = seq_per * mm; if (total_len > SEQ) total_len = SEQ;
  const bool dorope = s < total_len;
  int fi = 0, hi2 = 0, wi = 0;
  if (dorope) {
    int p = s % seq_per;
    fi = p / (h * wd);
    int rem = p - fi * (h * wd);
    hi2 = rem / wd;
    wi = rem - hi2 * wd;
  }
  float qv[3][2], kv[3][2];
  float sq = 0.f, sk = 0.f;
#pragma unroll
  for (int r = 0; r < 3; ++r) {
    int pi = t + r * 256;
    int head = pi >> 6;
    int dd = (pi & 63) * 2;
    size_t addr = (((size_t)(b * NH + head)) * SEQ + s) * HD + dd;
    __hip_bfloat162 q2 = *reinterpret_cast<const __hip_bfloat162*>(&qb[addr]);
    __hip_bfloat162 k2 = *reinterpret_cast<const __hip_bfloat162*>(&kb[addr]);
    qv[r][0] = __bfloat162float(q2.x); qv[r][1] = __bfloat162float(q2.y);
    kv[r][0] = __bfloat162float(k2.x); kv[r][1] = __bfloat162float(k2.y);
    sq += qv[r][0] * qv[r][0] + qv[r][1] * qv[r][1];
    sk += kv[r][0] * kv[r][0] + kv[r][1] * kv[r][1];
  }
#pragma unroll
  for (int off = 1; off < 64; off <<= 1) {
    sq += __shfl_xor(sq, off);
    sk += __shfl_xor(sk, off);
  }
  __shared__ float red[2][4];
  if ((t & 63) == 0) { red[0][t >> 6] = sq; red[1][t >> 6] = sk; }
  __syncthreads();
  float tq = red[0][0] + red[0][1] + red[0][2] + red[0][3];
  float tk = red[1][0] + red[1][1] + red[1][2] + red[1][3];
  float rq = rsqrtf(tq * (1.0f / DMODEL) + 1e-6f);
  float rk = rsqrtf(tk * (1.0f / DMODEL) + 1e-6f);
  const float scale = 0.08838834764831845f; // 1/sqrt(128), folded into q
#pragma unroll
  for (int r = 0; r < 3; ++r) {
    int pi = t + r * 256;
    int head = pi >> 6;
    int dd = (pi & 63) * 2;
    int col = pi * 2;
    size_t addr = (((size_t)(b * NH + head)) * SEQ + s) * HD + dd;
    float q0 = qv[r][0] * rq * gq[col], q1 = qv[r][1] * rq * gq[col + 1];
    float k0 = kv[r][0] * rk * gk[col], k1 = kv[r][1] * rk * gk[col + 1];
    if (dorope) {
      int j = pi & 63;
      int row = (j < 22) ? fi : (j < 43) ? hi2 : wi;
      float co = fc[row * 64 + j], si = fs[row * 64 + j];
      float a;
      a = q0 * co - q1 * si; q1 = q0 * si + q1 * co; q0 = a;
      a = k0 * co - k1 * si; k1 = k0 * si + k1 * co; k0 = a;
    }
    q0 *= scale; q1 *= scale;
    __hip_bfloat162 oq, ok;
    oq.x = __float2bfloat16(q0); oq.y = __float2bfloat16(q1);
    ok.x = __float2bfloat16(k0); ok.y = __float2bfloat16(k1);
    *reinterpret_cast<__hip_bfloat162*>(&qb[addr]) = oq;
    *reinterpret_cast<__hip_bfloat162*>(&kb[addr]) = ok;
  }
}

// ---------- flash attention v11 (R13/R18, best measured): K dbuf + V single-buffer ----------
__global__ __launch_bounds__(256, 2) void attn_kernel(
    const __hip_bfloat16* __restrict__ qb, const __hip_bfloat16* __restrict__ kbuf,
    const __hip_bfloat16* __restrict__ vt, const int* __restrict__ seq_lens,
    __hip_bfloat16* __restrict__ ob)
{
  const int orig = blockIdx.x;
  const int wg = (orig & 7) * 84 + (orig >> 3);
  const int bh = wg / 14, qt = wg % 14;
  const int bbb = bh / NH, hh = bh - bbb * NH;
  const int tid = threadIdx.x;
  const int w = tid >> 6, l = tid & 63;
  const int lq = l & 31, h = l >> 5;
  const int sl = seq_lens[bbb];
  const __hip_bfloat16* Q = qb + (size_t)bh * SEQ * HD;
  const char* Kc = (const char*)(kbuf + (size_t)bh * SEQ * HD);
  const __hip_bfloat16* Vp = vt + (size_t)bh * HD * SEQ;   // [128][1792]
  const int q0 = qt * 128 + w * 32;

  __shared__ __hip_bfloat16 Kt[2][64 * 128];   // 32 KB, 256B rows, ^((row&7)<<4)
  __shared__ __hip_bfloat16 Vt[128 * 64];      // 16 KB single buffer, 128B rows

  bf16x8 qf[8];
#pragma unroll
  for (int kc = 0; kc < 8; ++kc)
    qf[kc] = *reinterpret_cast<const bf16x8*>(
        &Q[(size_t)(q0 + lq) * HD + kc * 16 + h * 8]);

  f32x16 oacc[4] = {};                          // O[q_off][d0*32+lq]
  float m = -3e38f, ll = 0.f;                   // per-lane q-row softmax state

  const int nkt = (sl + 63) >> 6;

  auto stageK = [&](int buf, int k0) {
    char* Lb = (char*)&Kt[buf][0];
#pragma unroll
    for (int q2 = 0; q2 < 4; ++q2) {
      int chunk = q2 * 256 + tid;
      int row = chunk >> 4;
      int cb = (chunk & 15) << 4;
      int scb = cb ^ ((row & 7) << 4);
      gload16(Kc + (size_t)(k0 + row) * 256 + scb, Lb + chunk * 16);
    }
  };
  auto stageV = [&](int k0) {
    char* Lb = (char*)&Vt[0];
#pragma unroll
    for (int q2 = 0; q2 < 4; ++q2) {
      int chunk = q2 * 256 + tid;
      int row = chunk >> 3;
      int cb = (chunk & 7) << 4;
      int scb = cb ^ ((row & 7) << 4);
      gload16(Vp + (size_t)row * SEQ + k0 + (scb >> 1), Lb + chunk * 16);
    }
  };

  stageK(0, 0);
  for (int kt = 0; kt < nkt; ++kt) {
    __syncthreads();                            // K(kt) landed everywhere; Vt reads done
    const int k0 = kt * 64;
    stageV(k0);                                 // V first (oldest in vmcnt queue)
    const bool pf = (kt + 1 < nkt);
    if (pf) stageK((kt + 1) & 1, k0 + 64);      // K prefetch after
    const char* Kl = (const char*)&Kt[kt & 1][0];
    const char* Vl = (const char*)&Vt[0];

    // swapped QK^T: S^T[k][q], 16 ds_read_b128 + 16 mfma_32x32x16
    f32x16 sa[2] = {};
#pragma unroll
    for (int cb = 0; cb < 2; ++cb) {
      int row = cb * 32 + lq;
      int swz = (row & 7) << 4;
#pragma unroll
      for (int kc = 0; kc < 8; ++kc) {
        bf16x8 kf = *reinterpret_cast<const bf16x8*>(
            Kl + row * 256 + ((kc * 32 + h * 16) ^ swz));
        sa[cb] = __builtin_amdgcn_mfma_f32_32x32x16_bf16(kf, qf[kc], sa[cb], 0, 0, 0);
      }
    }

    // mask tail (rare)
    if (k0 + 64 > sl) {
#pragma unroll
      for (int cb = 0; cb < 2; ++cb)
#pragma unroll
        for (int r = 0; r < 16; ++r) {
          int kg = k0 + cb * 32 + (r & 3) + 8 * (r >> 2) + 4 * h;
          if (kg >= sl) sa[cb][r] = -3e38f;
        }
    }

    // in-register online softmax
    float mx = -3e38f;
#pragma unroll
    for (int cb = 0; cb < 2; ++cb)
#pragma unroll
      for (int r = 0; r < 16; ++r) mx = fmaxf(mx, sa[cb][r]);
    mx = fmaxf(mx, __shfl_xor(mx, 32));

    if (__any(mx - m > 8.f)) {                  // defer-max (T13)
      float mn = fmaxf(m, mx);
      float alpha = __expf(m - mn);
      m = mn;
      ll *= alpha;
#pragma unroll
      for (int r = 0; r < 16; ++r) {
        float ar = __shfl(alpha, (r & 3) + 8 * (r >> 2) + 4 * h);
#pragma unroll
        for (int d0 = 0; d0 < 4; ++d0) oacc[d0][r] *= ar;
      }
    }

    float rs = 0.f;
#pragma unroll
    for (int cb = 0; cb < 2; ++cb)
#pragma unroll
      for (int r = 0; r < 16; ++r) {
        float e = __expf(sa[cb][r] - m);
        sa[cb][r] = e;
        rs += e;
      }
    rs += __shfl_xor(rs, 32);
    ll += rs;

    // V(kt) visibility: my V retired (counted) + all waves' V retired (barrier)
    if (pf) asm volatile("s_waitcnt vmcnt(4)" ::: "memory");
    else    asm volatile("s_waitcnt vmcnt(0)" ::: "memory");
    __builtin_amdgcn_s_barrier();

    // P -> bf16 A-frags and PV (V from LDS)
#pragma unroll
    for (int c = 0; c < 4; ++c) {
      const int cb = c >> 1, r0 = 8 * (c & 1);
      unsigned A01 = pack2(sa[cb][r0],     sa[cb][r0 + 1]);
      unsigned A23 = pack2(sa[cb][r0 + 2], sa[cb][r0 + 3]);
      unsigned B01 = pack2(sa[cb][r0 + 4], sa[cb][r0 + 5]);
      unsigned B23 = pack2(sa[cb][r0 + 6], sa[cb][r0 + 7]);
      unsigned s1 = __shfl_xor(h ? A01 : B01, 32);
      unsigned s2 = __shfl_xor(h ? A23 : B23, 32);
      int4 wv;
      wv.x = (int)(h ? s1 : A01);
      wv.y = (int)(h ? s2 : A23);
      wv.z = (int)(h ? B01 : s1);
      wv.w = (int)(h ? B23 : s2);
      bf16x8 pa = *reinterpret_cast<bf16x8*>(&wv);
#pragma unroll
      for (int d0 = 0; d0 < 4; ++d0) {
        int vr = d0 * 32 + lq;
        bf16x8 vv = *reinterpret_cast<const bf16x8*>(
            Vl + vr * 128 + ((c * 32 + h * 16) ^ ((vr & 7) << 4)));
        oacc[d0] = __builtin_amdgcn_mfma_f32_32x32x16_bf16(pa, vv, oacc[d0], 0, 0, 0);
      }
    }
  }

  float invl = 1.0f / ll;
#pragma unroll
  for (int r = 0; r < 16; ++r) {
    int qoff = (r & 3) + 8 * (r >> 2) + 4 * h;
    float ir = __shfl(invl, qoff);
    int qrow = q0 + qoff;
#pragma unroll
    for (int d0 = 0; d0 < 4; ++d0)
      ob[((size_t)bbb * SEQ + qrow) * DMODEL + hh * HD + d0 * 32 + lq] =
          __float2bfloat16(oacc[d0][r] * ir);
  }
}

// ---------- launch ----------
extern "C" void kernel_launch(void* const* d_in, const int* in_sizes, int n_in,
                              void* d_out, int out_size, void* d_ws, size_t ws_size,
                              hipStream_t stream) {
  const float* x   = (const float*)d_in[0];
  const int* seq_lens   = (const int*)d_in[1];
  const int* grid_sizes = (const int*)d_in[2];
  const float* fc  = (const float*)d_in[3];
  const float* fs  = (const float*)d_in[4];
  const float* Wq  = (const float*)d_in[5];
  const float* bq  = (const float*)d_in[6];
  const float* Wk  = (const float*)d_in[7];
  const float* bk  = (const float*)d_in[8];
  const float* Wv  = (const float*)d_in[9];
  const float* bv  = (const float*)d_in[10];
  const float* Wo  = (const float*)d_in[11];
  const float* bo  = (const float*)d_in[12];
  const float* gq  = (const float*)d_in[13];
  const float* gk  = (const float*)d_in[14];
  const int* nmod  = (const int*)d_in[15];
  float* out = (float*)d_out;

  char* ws = (char*)d_ws;
  __hip_bfloat16* xb   = (__hip_bfloat16*)(ws + 0);           // [7168][1536]
  __hip_bfloat16* wb   = (__hip_bfloat16*)(ws + 22020096);    // [4608][1536]
  __hip_bfloat16* wob  = (__hip_bfloat16*)(ws + 36175872);    // [1536][1536]
  __hip_bfloat16* qbuf = (__hip_bfloat16*)(ws + 40894464);    // [48][1792][128]
  __hip_bfloat16* kbuf = (__hip_bfloat16*)(ws + 62914560);    // [48][1792][128]
  __hip_bfloat16* vtb  = (__hip_bfloat16*)(ws + 84934656);    // [48][128][1792]
  __hip_bfloat16* ob   = xb;                                  // O reuses xb region

  cast_all_kernel<<<(5111808 + 255) / 256, 256, 0, stream>>>(x, Wq, Wk, Wv, Wo, xb, wb, wob);

  // QKV: M=7168 (28 tiles of 256) x N=4608 (36 tiles of 128) -> 1008 = 8*126
  gemm_km<0><<<1008, 256, 0, stream>>>(xb, wb, 36, 126, bq, bk, bv,
                                       qbuf, kbuf, vtb, nullptr, nullptr);
  rmsrope_kernel<<<7168, 256, 0, stream>>>(qbuf, kbuf, gq, gk, fc, fs, grid_sizes, nmod);
  attn_kernel<<<672, 256, 0, stream>>>(qbuf, kbuf, vtb, seq_lens, ob);
  // out-proj: M=7168 (28) x N=1536 (12 tiles of 128) -> 336 = 8*42
  gemm_km<1><<<336, 256, 0, stream>>>(ob, wob, 12, 42, nullptr, nullptr, nullptr,
                                      nullptr, nullptr, nullptr, bo, out);
}